// Round 3
// baseline (144.051 us; speedup 1.0000x reference)
//
#include <hip/hip_runtime.h>
#include <hip/hip_bf16.h>
#include <math.h>

#define D      256
#define N2     8192
#define NHALF  4096

typedef __bf16 bf16x8_t __attribute__((ext_vector_type(8)));
typedef __bf16 bf16x4_t __attribute__((ext_vector_type(4)));
typedef float  f32x4_t  __attribute__((ext_vector_type(4)));

// ---------------- kernel 1: fused normalize + positives + denom-zero ----------------
__global__ __launch_bounds__(256) void prep_kernel(const float* __restrict__ a,
                                                   const float* __restrict__ b,
                                                   __bf16* __restrict__ zb,
                                                   float* __restrict__ g_pos,
                                                   float* __restrict__ g_denom) {
    const int tid = threadIdx.x;
    const int gt  = blockIdx.x * 256 + tid;
    if (gt < N2) g_denom[gt] = 0.0f;

    const int w = blockIdx.x * 4 + (tid >> 6);  // pair row in [0, NHALF)
    const int l = tid & 63;
    float4 x = ((const float4*)(a + (size_t)w * D))[l];
    float4 y = ((const float4*)(b + (size_t)w * D))[l];
    float sxx = x.x * x.x + x.y * x.y + x.z * x.z + x.w * x.w;
    float syy = y.x * y.x + y.y * y.y + y.z * y.z + y.w * y.w;
    float sxy = x.x * y.x + x.y * y.y + x.z * y.z + x.w * y.w;
    #pragma unroll
    for (int off = 32; off; off >>= 1) {
        sxx += __shfl_xor(sxx, off, 64);
        syy += __shfl_xor(syy, off, 64);
        sxy += __shfl_xor(sxy, off, 64);
    }
    const float rx = 1.0f / fmaxf(sqrtf(sxx), 1e-8f);
    const float ry = 1.0f / fmaxf(sqrtf(syy), 1e-8f);

    bf16x4_t ox, oy;
    ox[0] = (__bf16)(x.x * rx); ox[1] = (__bf16)(x.y * rx);
    ox[2] = (__bf16)(x.z * rx); ox[3] = (__bf16)(x.w * rx);
    oy[0] = (__bf16)(y.x * ry); oy[1] = (__bf16)(y.y * ry);
    oy[2] = (__bf16)(y.z * ry); oy[3] = (__bf16)(y.w * ry);
    *(bf16x4_t*)(zb + (size_t)w * D + l * 4)           = ox;
    *(bf16x4_t*)(zb + (size_t)(w + NHALF) * D + l * 4) = oy;

    if (l == 0) {
        const float p = sxy * rx * ry;
        g_pos[w]         = p;
        g_pos[w + NHALF] = p;
    }
}

// ---------------- kernel 2: full-matrix sim, row-sums only ----------------
// Round-2 diagnosis (arithmetic matches measured 79us within 4%): the compiler SINKS
// the A-panel loads into the strip loop, so every strip re-reads 32 KB/wave of A from
// L2 -> 2.6 GB L2 traffic -> L2-BW-bound (5850 cyc/strip model vs 5900 measured).
// An empty asm "+v" pin does not stop pre-RA sinking. Fix: load the A panel with
// OPAQUE inline-asm global_load_dwordx4 -- asm-defined values cannot be re-fetched or
// sunk, forcing the 128-VGPR panel to stay resident (budget ~233 <= 256 @ 2 blk/CU).
// B strips double-buffered in registers; 4 waves/block read identical B -> L1 bcast.
__global__ __launch_bounds__(256, 2) void sim_kernel(const __bf16* __restrict__ zb,
                                                     float* __restrict__ g_denom) {
    const int tid    = threadIdx.x;
    const int l      = tid & 63;
    const int lane15 = l & 15;
    const int quad   = l >> 4;

    const int rb = blockIdx.x >> 5;            // row block  [0,32)
    const int cb = blockIdx.x & 31;            // col chunk  [0,32)
    const int r0 = rb * 256 + (tid >> 6) * 64; // this wave's 64-row band
    const int c0 = cb * 256;                   // this wave's 256-col chunk

    // A fragments: 64 rows x K=256, loaded ONCE via opaque asm (cannot be sunk/remat)
    bf16x8_t af[4][8];
    {
        const __bf16* abase = zb + (size_t)(r0 + lane15) * D + quad * 8;
        #pragma unroll
        for (int mi = 0; mi < 4; ++mi) {
            #pragma unroll
            for (int kc = 0; kc < 8; ++kc) {
                const __bf16* p = abase + (size_t)mi * 16 * D + kc * 32;
                asm volatile("global_load_dwordx4 %0, %1, off"
                             : "=v"(af[mi][kc]) : "v"(p) : "memory");
            }
        }
        asm volatile("s_waitcnt vmcnt(0)" ::: "memory");
        __builtin_amdgcn_sched_barrier(0);
    }

    float rs[4] = {0.f, 0.f, 0.f, 0.f};

    bf16x8_t b0[8], b1[8];
    auto loadB = [&](int s, bf16x8_t* dst) {
        const __bf16* bbase = zb + (size_t)(c0 + s * 16 + lane15) * D + quad * 8;
        #pragma unroll
        for (int kc = 0; kc < 8; ++kc)
            dst[kc] = *(const bf16x8_t*)(bbase + kc * 32);
    };
    auto compute = [&](int s, const bf16x8_t* bfr) {
        f32x4_t acc[4] = {{0.f,0.f,0.f,0.f},{0.f,0.f,0.f,0.f},{0.f,0.f,0.f,0.f},{0.f,0.f,0.f,0.f}};
        #pragma unroll
        for (int kc = 0; kc < 8; ++kc)
            #pragma unroll
            for (int mi = 0; mi < 4; ++mi)
                acc[mi] = __builtin_amdgcn_mfma_f32_16x16x32_bf16(bfr[kc], af[mi][kc], acc[mi], 0, 0, 0);
        // acc[mi]: S-row = r0+16*mi+lane15 (lane), S-col = cs+quad*4+t (reg)
        const int cs = c0 + s * 16;
        const int dd = cs - r0;                // wave-uniform
        if (dd >= 0 && dd < 64) {
            // this strip contains the wave's diagonal block: zero self-similarity
            #pragma unroll
            for (int mi = 0; mi < 4; ++mi) {
                #pragma unroll
                for (int t = 0; t < 4; ++t) {
                    float e = __expf(2.0f * acc[mi][t]);
                    if (dd == 16 * mi && (quad * 4 + t) == lane15) e = 0.0f;
                    rs[mi] += e;
                }
            }
        } else {
            #pragma unroll
            for (int mi = 0; mi < 4; ++mi)
                #pragma unroll
                for (int t = 0; t < 4; ++t)
                    rs[mi] += __expf(2.0f * acc[mi][t]);
        }
    };

    loadB(0, b0);
    int s = 0;
    while (true) {
        if (s + 1 < 16) loadB(s + 1, b1);
        compute(s, b0);
        if (++s >= 16) break;
        if (s + 1 < 16) loadB(s + 1, b0);
        compute(s, b1);
        if (++s >= 16) break;
    }

    // row sums: 4 lanes (quads) share each row; reduce then one atomic per row
    #pragma unroll
    for (int mi = 0; mi < 4; ++mi) {
        rs[mi] += __shfl_xor(rs[mi], 16, 64);
        rs[mi] += __shfl_xor(rs[mi], 32, 64);
    }
    if (l < 16) {
        #pragma unroll
        for (int mi = 0; mi < 4; ++mi)
            atomicAdd(&g_denom[r0 + 16 * mi + l], rs[mi]);
    }
}

// ---------------- kernel 3: finalize -> scalar loss ----------------
__global__ __launch_bounds__(256) void fin_kernel(const float* __restrict__ g_denom,
                                                  const float* __restrict__ g_pos,
                                                  float* __restrict__ out) {
    const int tid = threadIdx.x;
    float local = 0.0f;
    for (int k = tid; k < N2; k += 256)
        local += logf(g_denom[k]) - 2.0f * g_pos[k];
    #pragma unroll
    for (int off = 32; off; off >>= 1) local += __shfl_xor(local, off, 64);
    __shared__ float sw[4];
    if ((tid & 63) == 0) sw[tid >> 6] = local;
    __syncthreads();
    if (tid == 0) out[0] = (sw[0] + sw[1] + sw[2] + sw[3]) / (float)N2;
}

extern "C" void kernel_launch(void* const* d_in, const int* in_sizes, int n_in,
                              void* d_out, int out_size, void* d_ws, size_t ws_size,
                              hipStream_t stream) {
    const float* emb_i = (const float*)d_in[0];
    const float* emb_j = (const float*)d_in[1];

    __bf16* zb      = (__bf16*)d_ws;                                 // 4 MB
    float*  g_denom = (float*)((char*)d_ws + (size_t)N2 * D * 2);    // 8192 fp32
    float*  g_pos   = g_denom + N2;                                  // 8192 fp32
    float*  out     = (float*)d_out;

    prep_kernel<<<NHALF / 4, 256, 0, stream>>>(emb_i, emb_j, zb, g_pos, g_denom);
    sim_kernel<<<1024, 256, 0, stream>>>(zb, g_denom);   // 4096 uniform waves
    fin_kernel<<<1, 256, 0, stream>>>(g_denom, g_pos, out);
}

// Round 4
// 142.894 us; speedup vs baseline: 1.0081x; 1.0081x over previous
//
#include <hip/hip_runtime.h>
#include <hip/hip_bf16.h>
#include <math.h>

#define D      256
#define N2     8192
#define NHALF  4096

typedef __bf16 bf16x8_t __attribute__((ext_vector_type(8)));
typedef __bf16 bf16x4_t __attribute__((ext_vector_type(4)));
typedef float  f32x4_t  __attribute__((ext_vector_type(4)));

// ---------------- kernel 1: fused normalize + positives + denom-zero ----------------
__global__ __launch_bounds__(256) void prep_kernel(const float* __restrict__ a,
                                                   const float* __restrict__ b,
                                                   __bf16* __restrict__ zb,
                                                   float* __restrict__ g_pos,
                                                   float* __restrict__ g_denom) {
    const int tid = threadIdx.x;
    const int gt  = blockIdx.x * 256 + tid;
    if (gt < N2) g_denom[gt] = 0.0f;

    const int w = blockIdx.x * 4 + (tid >> 6);  // pair row in [0, NHALF)
    const int l = tid & 63;
    float4 x = ((const float4*)(a + (size_t)w * D))[l];
    float4 y = ((const float4*)(b + (size_t)w * D))[l];
    float sxx = x.x * x.x + x.y * x.y + x.z * x.z + x.w * x.w;
    float syy = y.x * y.x + y.y * y.y + y.z * y.z + y.w * y.w;
    float sxy = x.x * y.x + x.y * y.y + x.z * y.z + x.w * y.w;
    #pragma unroll
    for (int off = 32; off; off >>= 1) {
        sxx += __shfl_xor(sxx, off, 64);
        syy += __shfl_xor(syy, off, 64);
        sxy += __shfl_xor(sxy, off, 64);
    }
    const float rx = 1.0f / fmaxf(sqrtf(sxx), 1e-8f);
    const float ry = 1.0f / fmaxf(sqrtf(syy), 1e-8f);

    bf16x4_t ox, oy;
    ox[0] = (__bf16)(x.x * rx); ox[1] = (__bf16)(x.y * rx);
    ox[2] = (__bf16)(x.z * rx); ox[3] = (__bf16)(x.w * rx);
    oy[0] = (__bf16)(y.x * ry); oy[1] = (__bf16)(y.y * ry);
    oy[2] = (__bf16)(y.z * ry); oy[3] = (__bf16)(y.w * ry);
    *(bf16x4_t*)(zb + (size_t)w * D + l * 4)           = ox;
    *(bf16x4_t*)(zb + (size_t)(w + NHALF) * D + l * 4) = oy;

    if (l == 0) {
        const float p = sxy * rx * ry;
        g_pos[w]         = p;
        g_pos[w + NHALF] = p;
    }
}

// ---------------- kernel 2: full-matrix sim, row-sums only ----------------
// Round-3 diagnosis: opaque-asm A loads + VGPR_Count stuck at 120 proves the
// ALLOCATOR SPILLED the 128-VGPR A panel to scratch -- the 256-VGPR cap implied by
// __launch_bounds__(256,2) is just below the true demand (~240), and the allocator
// evicts the longest-lived range (af), recreating the per-strip 32KB/wave re-read
// (now from scratch) that L2-BW-bounds the kernel at ~79us. Fix: launch_bounds
// (256,1) -> cap 512, allocator keeps the panel; final VGPR ~240 still gives
// 2 waves/SIMD. A loads stay opaque-asm so they cannot be re-sunk. B strips
// double-buffered from global; 4 waves/block share B strips -> L1 broadcast.
__global__ __launch_bounds__(256, 1) void sim_kernel(const __bf16* __restrict__ zb,
                                                     float* __restrict__ g_denom) {
    const int tid    = threadIdx.x;
    const int l      = tid & 63;
    const int lane15 = l & 15;
    const int quad   = l >> 4;

    const int rb = blockIdx.x >> 5;            // row block  [0,32)
    const int cb = blockIdx.x & 31;            // col chunk  [0,32)
    const int r0 = rb * 256 + (tid >> 6) * 64; // this wave's 64-row band
    const int c0 = cb * 256;                   // this wave's 256-col chunk

    // A fragments: 64 rows x K=256, loaded ONCE via opaque asm (cannot be sunk/remat)
    bf16x8_t af[4][8];
    {
        const __bf16* abase = zb + (size_t)(r0 + lane15) * D + quad * 8;
        #pragma unroll
        for (int mi = 0; mi < 4; ++mi) {
            #pragma unroll
            for (int kc = 0; kc < 8; ++kc) {
                const __bf16* p = abase + (size_t)mi * 16 * D + kc * 32;
                asm volatile("global_load_dwordx4 %0, %1, off"
                             : "=v"(af[mi][kc]) : "v"(p) : "memory");
            }
        }
        asm volatile("s_waitcnt vmcnt(0)" ::: "memory");
        __builtin_amdgcn_sched_barrier(0);
    }

    float rs[4] = {0.f, 0.f, 0.f, 0.f};

    bf16x8_t b0[8], b1[8];
    auto loadB = [&](int s, bf16x8_t* dst) {
        const __bf16* bbase = zb + (size_t)(c0 + s * 16 + lane15) * D + quad * 8;
        #pragma unroll
        for (int kc = 0; kc < 8; ++kc)
            dst[kc] = *(const bf16x8_t*)(bbase + kc * 32);
    };
    auto compute = [&](int s, const bf16x8_t* bfr) {
        f32x4_t acc[4] = {{0.f,0.f,0.f,0.f},{0.f,0.f,0.f,0.f},{0.f,0.f,0.f,0.f},{0.f,0.f,0.f,0.f}};
        #pragma unroll
        for (int kc = 0; kc < 8; ++kc)
            #pragma unroll
            for (int mi = 0; mi < 4; ++mi)
                acc[mi] = __builtin_amdgcn_mfma_f32_16x16x32_bf16(bfr[kc], af[mi][kc], acc[mi], 0, 0, 0);
        // acc[mi]: S-row = r0+16*mi+lane15 (lane), S-col = cs+quad*4+t (reg)
        const int cs = c0 + s * 16;
        const int dd = cs - r0;                // wave-uniform
        if (dd >= 0 && dd < 64) {
            // this strip contains the wave's diagonal block: zero self-similarity
            #pragma unroll
            for (int mi = 0; mi < 4; ++mi) {
                #pragma unroll
                for (int t = 0; t < 4; ++t) {
                    float e = __expf(2.0f * acc[mi][t]);
                    if (dd == 16 * mi && (quad * 4 + t) == lane15) e = 0.0f;
                    rs[mi] += e;
                }
            }
        } else {
            #pragma unroll
            for (int mi = 0; mi < 4; ++mi)
                #pragma unroll
                for (int t = 0; t < 4; ++t)
                    rs[mi] += __expf(2.0f * acc[mi][t]);
        }
    };

    loadB(0, b0);
    int s = 0;
    while (true) {
        if (s + 1 < 16) loadB(s + 1, b1);
        compute(s, b0);
        if (++s >= 16) break;
        if (s + 1 < 16) loadB(s + 1, b0);
        compute(s, b1);
        if (++s >= 16) break;
    }

    // row sums: 4 lanes (quads) share each row; reduce then one atomic per row
    #pragma unroll
    for (int mi = 0; mi < 4; ++mi) {
        rs[mi] += __shfl_xor(rs[mi], 16, 64);
        rs[mi] += __shfl_xor(rs[mi], 32, 64);
    }
    if (l < 16) {
        #pragma unroll
        for (int mi = 0; mi < 4; ++mi)
            atomicAdd(&g_denom[r0 + 16 * mi + l], rs[mi]);
    }
}

// ---------------- kernel 3: finalize -> scalar loss ----------------
__global__ __launch_bounds__(256) void fin_kernel(const float* __restrict__ g_denom,
                                                  const float* __restrict__ g_pos,
                                                  float* __restrict__ out) {
    const int tid = threadIdx.x;
    float local = 0.0f;
    for (int k = tid; k < N2; k += 256)
        local += logf(g_denom[k]) - 2.0f * g_pos[k];
    #pragma unroll
    for (int off = 32; off; off >>= 1) local += __shfl_xor(local, off, 64);
    __shared__ float sw[4];
    if ((tid & 63) == 0) sw[tid >> 6] = local;
    __syncthreads();
    if (tid == 0) out[0] = (sw[0] + sw[1] + sw[2] + sw[3]) / (float)N2;
}

extern "C" void kernel_launch(void* const* d_in, const int* in_sizes, int n_in,
                              void* d_out, int out_size, void* d_ws, size_t ws_size,
                              hipStream_t stream) {
    const float* emb_i = (const float*)d_in[0];
    const float* emb_j = (const float*)d_in[1];

    __bf16* zb      = (__bf16*)d_ws;                                 // 4 MB
    float*  g_denom = (float*)((char*)d_ws + (size_t)N2 * D * 2);    // 8192 fp32
    float*  g_pos   = g_denom + N2;                                  // 8192 fp32
    float*  out     = (float*)d_out;

    prep_kernel<<<NHALF / 4, 256, 0, stream>>>(emb_i, emb_j, zb, g_pos, g_denom);
    sim_kernel<<<1024, 256, 0, stream>>>(zb, g_denom);   // 4096 uniform waves
    fin_kernel<<<1, 256, 0, stream>>>(g_denom, g_pos, out);
}

// Round 5
// 130.946 us; speedup vs baseline: 1.1001x; 1.0912x over previous
//
#include <hip/hip_runtime.h>
#include <hip/hip_bf16.h>
#include <math.h>

#define D      256
#define N2     8192
#define NHALF  4096

#define BM   128        // block tile rows/cols
#define BK   64         // K chunk
#define NC   4          // 256 / BK
#define LDW  68         // LDS row stride in bf16 (BK + 4 pad -> 136 B, breaks bank alias)

typedef __bf16 bf16x8_t __attribute__((ext_vector_type(8)));
typedef __bf16 bf16x4_t __attribute__((ext_vector_type(4)));
typedef float  f32x4_t  __attribute__((ext_vector_type(4)));

// ---------------- kernel 1: fused normalize + positives + denom-zero ----------------
__global__ __launch_bounds__(256) void prep_kernel(const float* __restrict__ a,
                                                   const float* __restrict__ b,
                                                   __bf16* __restrict__ zb,
                                                   float* __restrict__ g_pos,
                                                   float* __restrict__ g_denom) {
    const int tid = threadIdx.x;
    const int gt  = blockIdx.x * 256 + tid;
    if (gt < N2) g_denom[gt] = 0.0f;

    const int w = blockIdx.x * 4 + (tid >> 6);  // pair row in [0, NHALF)
    const int l = tid & 63;
    float4 x = ((const float4*)(a + (size_t)w * D))[l];
    float4 y = ((const float4*)(b + (size_t)w * D))[l];
    float sxx = x.x * x.x + x.y * x.y + x.z * x.z + x.w * x.w;
    float syy = y.x * y.x + y.y * y.y + y.z * y.z + y.w * y.w;
    float sxy = x.x * y.x + x.y * y.y + x.z * y.z + x.w * y.w;
    #pragma unroll
    for (int off = 32; off; off >>= 1) {
        sxx += __shfl_xor(sxx, off, 64);
        syy += __shfl_xor(syy, off, 64);
        sxy += __shfl_xor(sxy, off, 64);
    }
    const float rx = 1.0f / fmaxf(sqrtf(sxx), 1e-8f);
    const float ry = 1.0f / fmaxf(sqrtf(syy), 1e-8f);

    bf16x4_t ox, oy;
    ox[0] = (__bf16)(x.x * rx); ox[1] = (__bf16)(x.y * rx);
    ox[2] = (__bf16)(x.z * rx); ox[3] = (__bf16)(x.w * rx);
    oy[0] = (__bf16)(y.x * ry); oy[1] = (__bf16)(y.y * ry);
    oy[2] = (__bf16)(y.z * ry); oy[3] = (__bf16)(y.w * ry);
    *(bf16x4_t*)(zb + (size_t)w * D + l * 4)           = ox;
    *(bf16x4_t*)(zb + (size_t)(w + NHALF) * D + l * 4) = oy;

    if (l == 0) {
        const float p = sxy * rx * ry;
        g_pos[w]         = p;
        g_pos[w + NHALF] = p;
    }
}

// ---------------- kernel 2: LDS-tiled full-matrix sim (m97-style GEMM) ----------------
// Rounds 1-4 post-mortem: the scheduler/allocator refuses to keep a 128-VGPR A panel
// live across the strip loop (sinks the loads, or spills volatile-asm loads to
// scratch), recreating a 32KB/wave/strip L2 re-read -> pinned at ~80us. Fix: classic
// LDS tiling with 2D register blocking so per-iteration register demand is ~150 and
// the only long-lived registers are the loop-carried MFMA accumulators (unsinkable).
//   grid 64x64 blocks of 128x128; 4 waves/block, wave tile 64x64 (acc 4x4 frags);
//   K=256 in 4 chunks of BK=64; A/B chunk tiles reg-staged into double-buffered LDS
//   (68 KB -> 2 blocks/CU); +8B row pad spreads ds_read_b128 across banks.
// Model/CU: MFMA 16.5us, LDS-read 20.5us, exp ~5us, L2 staging 15us -> ~25us.
__global__ __launch_bounds__(256, 2) void sim_kernel(const __bf16* __restrict__ zb,
                                                     float* __restrict__ g_denom) {
    __shared__ __bf16 ldsA[2][BM * LDW];
    __shared__ __bf16 ldsB[2][BM * LDW];

    const int tid    = threadIdx.x;
    const int l      = tid & 63;
    const int lane15 = l & 15;
    const int quad   = l >> 4;
    const int w      = tid >> 6;
    const int wr     = (w >> 1) * 64;          // wave row offset in block tile
    const int wc     = (w & 1) * 64;           // wave col offset in block tile

    const int bi = blockIdx.x >> 6;            // row block [0,64)
    const int bj = blockIdx.x & 63;            // col block [0,64)

    // staging map: thread t -> row r = t>>1, half = t&1 (64 B each), 4 x b128 units
    const int r    = tid >> 1;
    const int half = tid & 1;
    const __bf16* ga = zb + (size_t)(bi * BM + r) * D + half * 32;
    const __bf16* gb = zb + (size_t)(bj * BM + r) * D + half * 32;
    const int wofs = r * LDW + half * 32;

    bf16x8_t sa[4], sb[4];
    auto load_regs = [&](int c) {
        const int k0 = c * BK;
        #pragma unroll
        for (int u = 0; u < 4; ++u) {
            sa[u] = *(const bf16x8_t*)(ga + k0 + u * 8);
            sb[u] = *(const bf16x8_t*)(gb + k0 + u * 8);
        }
    };
    auto write_lds = [&](int buf) {
        #pragma unroll
        for (int u = 0; u < 4; ++u) {
            *(bf16x8_t*)(&ldsA[buf][wofs + u * 8]) = sa[u];
            *(bf16x8_t*)(&ldsB[buf][wofs + u * 8]) = sb[u];
        }
    };

    f32x4_t acc[4][4];
    #pragma unroll
    for (int mi = 0; mi < 4; ++mi)
        #pragma unroll
        for (int nj = 0; nj < 4; ++nj)
            acc[mi][nj] = (f32x4_t){0.f, 0.f, 0.f, 0.f};

    auto compute = [&](int buf) {
        #pragma unroll
        for (int ks = 0; ks < 2; ++ks) {
            bf16x8_t af[4], bf[4];
            #pragma unroll
            for (int mi = 0; mi < 4; ++mi)
                af[mi] = *(const bf16x8_t*)(&ldsA[buf][(wr + mi * 16 + lane15) * LDW + ks * 32 + quad * 8]);
            #pragma unroll
            for (int nj = 0; nj < 4; ++nj)
                bf[nj] = *(const bf16x8_t*)(&ldsB[buf][(wc + nj * 16 + lane15) * LDW + ks * 32 + quad * 8]);
            #pragma unroll
            for (int mi = 0; mi < 4; ++mi)
                #pragma unroll
                for (int nj = 0; nj < 4; ++nj)
                    acc[mi][nj] = __builtin_amdgcn_mfma_f32_16x16x32_bf16(bf[nj], af[mi], acc[mi][nj], 0, 0, 0);
        }
    };

    // prologue: stage chunk 0
    load_regs(0);
    write_lds(0);
    __syncthreads();

    int cur = 0;
    #pragma unroll
    for (int c = 0; c < NC; ++c) {
        if (c + 1 < NC) load_regs(c + 1);
        compute(cur);
        if (c + 1 < NC) {
            write_lds(cur ^ 1);     // safe: buf[cur^1] readers all passed prior barrier
            __syncthreads();
            cur ^= 1;
        }
    }

    // epilogue: e = exp(sim/T) = exp2(acc * 2/ln2); zero self-similarity; row sums
    // acc[mi][nj]: S-row = bi*128 + wr + mi*16 + lane15, S-col = bj*128 + wc + nj*16 + quad*4 + t
    const bool dw = (bi == bj) && (wr == wc);
    float rs[4] = {0.f, 0.f, 0.f, 0.f};
    #pragma unroll
    for (int mi = 0; mi < 4; ++mi) {
        #pragma unroll
        for (int nj = 0; nj < 4; ++nj) {
            #pragma unroll
            for (int t = 0; t < 4; ++t) {
                float e = exp2f(acc[mi][nj][t] * 2.8853900817779268f);
                if (dw && mi == nj && (quad * 4 + t) == lane15) e = 0.0f;
                rs[mi] += e;
            }
        }
    }
    // reduce the 4 quads holding the same row, then one atomic per row
    #pragma unroll
    for (int mi = 0; mi < 4; ++mi) {
        rs[mi] += __shfl_xor(rs[mi], 16, 64);
        rs[mi] += __shfl_xor(rs[mi], 32, 64);
    }
    if (l < 16) {
        #pragma unroll
        for (int mi = 0; mi < 4; ++mi)
            atomicAdd(&g_denom[bi * BM + wr + mi * 16 + l], rs[mi]);
    }
}

// ---------------- kernel 3: finalize -> scalar loss ----------------
__global__ __launch_bounds__(256) void fin_kernel(const float* __restrict__ g_denom,
                                                  const float* __restrict__ g_pos,
                                                  float* __restrict__ out) {
    const int tid = threadIdx.x;
    float local = 0.0f;
    for (int k = tid; k < N2; k += 256)
        local += logf(g_denom[k]) - 2.0f * g_pos[k];
    #pragma unroll
    for (int off = 32; off; off >>= 1) local += __shfl_xor(local, off, 64);
    __shared__ float sw[4];
    if ((tid & 63) == 0) sw[tid >> 6] = local;
    __syncthreads();
    if (tid == 0) out[0] = (sw[0] + sw[1] + sw[2] + sw[3]) / (float)N2;
}

extern "C" void kernel_launch(void* const* d_in, const int* in_sizes, int n_in,
                              void* d_out, int out_size, void* d_ws, size_t ws_size,
                              hipStream_t stream) {
    const float* emb_i = (const float*)d_in[0];
    const float* emb_j = (const float*)d_in[1];

    __bf16* zb      = (__bf16*)d_ws;                                 // 4 MB
    float*  g_denom = (float*)((char*)d_ws + (size_t)N2 * D * 2);    // 8192 fp32
    float*  g_pos   = g_denom + N2;                                  // 8192 fp32
    float*  out     = (float*)d_out;

    prep_kernel<<<NHALF / 4, 256, 0, stream>>>(emb_i, emb_j, zb, g_pos, g_denom);
    sim_kernel<<<64 * 64, 256, 0, stream>>>(zb, g_denom);
    fin_kernel<<<1, 256, 0, stream>>>(g_denom, g_pos, out);
}